// Round 13
// baseline (85.597 us; speedup 1.0000x reference)
//
#include <hip/hip_runtime.h>
#include <hip/hip_bf16.h>

#define BB     64
#define NF4    200000        // NTOT / 4
#define CHUNKS 3125          // NF4 / 64
#define NP     128
#define NH1    256
#define NH2    128
#define NC     32
#define EPSV   1e-5f

typedef float fx4 __attribute__((ext_vector_type(4)));

#define AS_G __attribute__((address_space(1)))
#define AS_L __attribute__((address_space(3)))

__device__ __forceinline__ float dot4(fx4 a, fx4 b) {
    return fmaf(a[0], b[0], fmaf(a[1], b[1], fmaf(a[2], b[2], a[3] * b[3])));
}

__device__ __forceinline__ int bitrev3(int l) {
    return ((l & 1) << 2) | (l & 2) | ((l & 4) >> 2);
}

template <int C, int M>
__device__ __forceinline__ void red_step(float* v, int lane) {
    const bool hi = (lane & M) != 0;
    #pragma unroll
    for (int j = 0; j < C / 2; ++j) {
        float mine  = hi ? v[j + C / 2] : v[j];
        float other = hi ? v[j]         : v[j + C / 2];
        v[j] = mine + __shfl_xor(other, M);
    }
}

// Full reduce of acc[8]: returns (on every lane) the total for batch
// bitrev3(lane&7) within this octet.
__device__ __forceinline__ float reduce8(float* acc, int lane) {
    red_step<8, 1>(acc, lane);
    red_step<4, 2>(acc, lane);
    red_step<2, 4>(acc, lane);
    float s = acc[0];
    s += __shfl_xor(s, 8);
    s += __shfl_xor(s, 16);
    s += __shfl_xor(s, 32);
    return s;
}

// ---------------------------------------------------------------------------
// Scatter-reduce: WX[b, idx[n]] += x[b,n] * w[n]     (idx sorted)
// One wave per 64-quad chunk; w/idx loaded ONCE; 8 batch-octet items
// walked with a 2-slot LDS-DMA double buffer and FIXED-COUNT vmcnt waits
// (8 / 9 / 1) that never drain the pipeline: next item's 8 loads + exactly
// one outstanding atomic stay in flight across every consume. Exactly ONE
// atomic instruction per item (16-lane combined pLo/pHi on boundary
// chunks) keeps the queue arithmetic exact. Consume is asm ds_read_b128 +
// lgkmcnt(0) + sched_barrier(0) so the compiler cannot insert its own
// serializing waits.
// ---------------------------------------------------------------------------
__global__ __launch_bounds__(128) void k_scatter(
    const float* __restrict__ x, const float* __restrict__ w,
    const int* __restrict__ idx, float* __restrict__ WX)
{
    __shared__ fx4 lds4[2 * 2 * 8 * 64];   // [wave][slot][row][lane] = 32 KB
    const int tid  = threadIdx.x;
    const int lane = tid & 63;
    const int q    = tid >> 6;             // wave in block: 0..1
    const int ch   = blockIdx.x * 2 + q;
    if (ch >= CHUNKS) return;              // wave-uniform exit
    const int n4   = ch * 64 + lane;

    const fx4*  __restrict__ w4 = reinterpret_cast<const fx4*>(w);
    const int4* __restrict__ p4 = reinterpret_cast<const int4*>(idx);
    const fx4*  __restrict__ x4 = reinterpret_cast<const fx4*>(x);

    const fx4  wv = w4[n4];
    const int4 pv = p4[n4];
    const int  pLo = __builtin_amdgcn_readfirstlane(pv.x);
    const int  pHi = __shfl(pv.w, 63);     // last element's pathway
    const bool uniform = (pLo == pHi);

    fx4 wLo, wHi;
    wLo[0] = (pv.x == pLo) ? wv[0] : 0.f;  wHi[0] = (pv.x == pHi) ? wv[0] : 0.f;
    wLo[1] = (pv.y == pLo) ? wv[1] : 0.f;  wHi[1] = (pv.y == pHi) ? wv[1] : 0.f;
    wLo[2] = (pv.z == pLo) ? wv[2] : 0.f;  wHi[2] = (pv.z == pHi) ? wv[2] : 0.f;
    wLo[3] = (pv.w == pLo) ? wv[3] : 0.f;  wHi[3] = (pv.w == pHi) ? wv[3] : 0.f;

    fx4* const base = lds4 + q * (2 * 8 * 64);   // wave-private 16 KB

    auto dma = [&](int o) {                // stage octet o into slot o&1
        const int s = o & 1;
        #pragma unroll
        for (int i = 0; i < 8; ++i) {
            const float* gp = (const float*)(x4 + ((size_t)(o * 8 + i) * NF4 + n4));
            __builtin_amdgcn_global_load_lds((const AS_G float*)gp,
                                             (AS_L float*)(base + (s * 8 + i) * 64),
                                             16, 0, 0);
        }
    };

    dma(0); dma(1);                        // prologue: 16 loads in flight

    #pragma unroll
    for (int o = 0; o < 8; ++o) {
        // Fixed-count waits: queue = [dma(o) 8][atomic(o-1) 1][dma(o+1) 8]
        if (o == 0)      asm volatile("s_waitcnt vmcnt(8)" ::: "memory");
        else if (o < 7)  asm volatile("s_waitcnt vmcnt(9)" ::: "memory");
        else             asm volatile("s_waitcnt vmcnt(1)" ::: "memory");

        const int s = o & 1;
        fx4 xr[8];
        #pragma unroll
        for (int i = 0; i < 8; ++i) {      // asm consume: compiler-invisible
            const unsigned laddr =
                (unsigned)(size_t)(AS_L char*)(base + (s * 8 + i) * 64 + lane);
            asm volatile("ds_read_b128 %0, %1" : "=v"(xr[i]) : "v"(laddr));
        }
        asm volatile("s_waitcnt lgkmcnt(0)" ::: "memory");
        __builtin_amdgcn_sched_barrier(0);  // rule #18: no hoist past lgkmcnt

        float acc[8], accH[8];
        #pragma unroll
        for (int i = 0; i < 8; ++i)
            acc[i] = dot4(xr[i], wLo);
        const float sLo = reduce8(acc, lane);
        float sHi = 0.f;
        if (!uniform) {                     // wave-uniform branch
            #pragma unroll
            for (int i = 0; i < 8; ++i)
                accH[i] = dot4(xr[i], wHi);
            sHi = reduce8(accH, lane);
        }
        const int   b0  = o * 8;
        const float val = (lane < 8) ? sLo : sHi;
        const int   col = (lane < 8) ? pLo : pHi;
        const int   nl  = uniform ? 8 : 16;
        if (lane < nl)                      // exactly ONE atomic instruction
            atomicAdd(&WX[(b0 + bitrev3(lane & 7)) * NP + col], val);

        __builtin_amdgcn_sched_barrier(0);
        if (o + 2 < 8) dma(o + 2);          // refill freed slot
        __builtin_amdgcn_sched_barrier(0);
    }
}

// ---------------------------------------------------------------------------
// Zero WX (replaces hipMemsetAsync; PMC-visible).
// ---------------------------------------------------------------------------
__global__ void k_zero(float* __restrict__ WX)
{
    const int i = blockIdx.x * 256 + threadIdx.x;
    if (i < BB * NP) WX[i] = 0.f;
}

__device__ __forceinline__ float bn_shfl(float a, float gj, float bj)
{
    float s = a, q = a * a;
    #pragma unroll
    for (int off = 32; off > 0; off >>= 1) {
        s += __shfl_xor(s, off);
        q += __shfl_xor(q, off);
    }
    const float m   = s * (1.f / BB);
    const float var = q * (1.f / BB) - m * m;
    return (a - m) * rsqrtf(var + EPSV) * gj + bj;
}

// ---------------------------------------------------------------------------
// BN0+gate (redundant per block, parallel) + fc1 + ReLU + BN1.
// ---------------------------------------------------------------------------
__global__ __launch_bounds__(256) void k_fc1z(
    const float* __restrict__ WX,   const float* __restrict__ co_w,
    const float* __restrict__ bn0g, const float* __restrict__ bn0b,
    const float* __restrict__ W1,   const float* __restrict__ b1,
    const float* __restrict__ bn1g, const float* __restrict__ bn1b,
    float* __restrict__ Zout, float* __restrict__ h1t)
{
    __shared__ float Zl[NP * 65];    // pad 65: conflict-free write & read
    const int tid  = threadIdx.x;
    const int wv   = tid >> 6;
    const int lane = tid & 63;       // == batch in fc1 stage
    const int blk  = blockIdx.x;

    if (tid < NP) {
        const int p = tid;
        float sum = 0.f, sq = 0.f;
        #pragma unroll 8
        for (int b = 0; b < BB; ++b) {
            const float r = fmaxf(WX[b * NP + p], 0.f);
            sum += r; sq += r * r;
        }
        const float m   = sum * (1.f / BB);
        const float var = sq * (1.f / BB) - m * m;
        const float sc  = rsqrtf(var + EPSV) * bn0g[p];
        const float bt  = bn0b[p];
        const float sig = 1.f / (1.f + expf(-co_w[p]));
        #pragma unroll 8
        for (int b = 0; b < BB; ++b) {
            const float r = fmaxf(WX[b * NP + p], 0.f);
            const float z = ((r - m) * sc + bt) * sig;
            Zl[p * 65 + b] = z;
            if (blk == 0) Zout[b * NP + p] = z;
        }
    }
    __syncthreads();

    const int j = blk * 4 + wv;      // 0..255
    float acc = b1[j];
    #pragma unroll 8
    for (int k = 0; k < NP; ++k)
        acc = fmaf(Zl[k * 65 + lane], W1[k * NH1 + j], acc);
    h1t[j * BB + lane] = bn_shfl(fmaxf(acc, 0.f), bn1g[j], bn1b[j]);
}

// ---------------------------------------------------------------------------
// fc2 + ReLU + BN2 from TRANSPOSED input [K][BB]. One block per column j.
// ---------------------------------------------------------------------------
template <int K, int NOUT>
__global__ void k_fc_bn_t(const float* __restrict__ in_t,  // [K][BB]
                          const float* __restrict__ W,     // [K, NOUT]
                          const float* __restrict__ bias,
                          const float* __restrict__ g,
                          const float* __restrict__ beta,
                          float* __restrict__ out_t)       // [NOUT][BB]
{
    const int j = blockIdx.x;
    const int b = threadIdx.x;  // 0..63
    float acc = bias[j];
    #pragma unroll 8
    for (int k = 0; k < K; ++k)
        acc = fmaf(in_t[k * BB + b], W[k * NOUT + j], acc);
    out_t[j * BB + b] = bn_shfl(fmaxf(acc, 0.f), g[j], beta[j]);
}

// ---------------------------------------------------------------------------
// Final Linear + row softmax from transposed h2 [NH2][BB].
// ---------------------------------------------------------------------------
__global__ void k_head(const float* __restrict__ h2t,  // [NH2][BB]
                       const float* __restrict__ Wo,   // [NH2, NC]
                       const float* __restrict__ bo,
                       float* __restrict__ y)          // [BB, NC]
{
    const int b = blockIdx.x;
    const int c = threadIdx.x;  // 0..31
    float acc = bo[c];
    #pragma unroll 8
    for (int k = 0; k < NH2; ++k)
        acc = fmaf(h2t[k * BB + b], Wo[k * NC + c], acc);
    float mx = acc;
    #pragma unroll
    for (int off = 16; off > 0; off >>= 1)
        mx = fmaxf(mx, __shfl_xor(mx, off));
    const float e = expf(acc - mx);
    float s = e;
    #pragma unroll
    for (int off = 16; off > 0; off >>= 1)
        s += __shfl_xor(s, off);
    y[b * NC + c] = e / s;
}

// ---------------------------------------------------------------------------
extern "C" void kernel_launch(void* const* d_in, const int* in_sizes, int n_in,
                              void* d_out, int out_size, void* d_ws, size_t ws_size,
                              hipStream_t stream)
{
    const float* x    = (const float*)d_in[0];
    const float* w    = (const float*)d_in[1];
    const float* co_w = (const float*)d_in[2];
    const float* bn0g = (const float*)d_in[3];
    const float* bn0b = (const float*)d_in[4];
    const float* W1   = (const float*)d_in[5];
    const float* b1   = (const float*)d_in[6];
    const float* bn1g = (const float*)d_in[7];
    const float* bn1b = (const float*)d_in[8];
    const float* W2   = (const float*)d_in[9];
    const float* b2   = (const float*)d_in[10];
    const float* bn2g = (const float*)d_in[11];
    const float* bn2b = (const float*)d_in[12];
    const float* Wo   = (const float*)d_in[13];
    const float* bo   = (const float*)d_in[14];
    const int*   idx  = (const int*)d_in[15];

    float* out = (float*)d_out;
    float* y   = out;               // [64, 32]  (output 0)
    float* Z   = out + BB * NC;     // [64, 128] (output 1)

    float* WX  = (float*)d_ws;          // 8192 f32
    float* h1t = WX + BB * NP;          // 16384 f32  [j][b]
    float* h2t = h1t + BB * NH1;        // 8192 f32   [j][b]

    k_zero<<<32, 256, 0, stream>>>(WX);
    k_scatter<<<(CHUNKS + 1) / 2, 128, 0, stream>>>(x, w, idx, WX);
    k_fc1z<<<64, 256, 0, stream>>>(WX, co_w, bn0g, bn0b,
                                   W1, b1, bn1g, bn1b, Z, h1t);
    k_fc_bn_t<NH1, NH2><<<NH2, BB, 0, stream>>>(h1t, W2, b2, bn2g, bn2b, h2t);
    k_head<<<BB, NC, 0, stream>>>(h2t, Wo, bo, y);
}